// Round 1
// baseline (756.056 us; speedup 1.0000x reference)
//
#include <hip/hip_runtime.h>
#include <hip/hip_bf16.h>
#include <stdint.h>

#define N_NODES 100000
#define IN_CH   128
#define HID     128
#define OUT_CH  64
#define N_EDGES 1600000

#define NB    196      // buckets of 512 nodes
#define NBLK  250      // edge-partition blocks for phases A/B
#define EPB   6400     // edges per block

typedef __attribute__((ext_vector_type(8))) short  bf16x8;
typedef __attribute__((ext_vector_type(4))) float  f32x4;

// ---------------- helpers ----------------

__device__ __forceinline__ unsigned short f2bf(float f) {   // RNE f32->bf16
    unsigned int u = __float_as_uint(f);
    u = (u + 0x7fffu + ((u >> 16) & 1u)) >> 16;
    return (unsigned short)u;
}
__device__ __forceinline__ float bfl(unsigned int u) { return __uint_as_float(u << 16); }
__device__ __forceinline__ float bfh(unsigned int u) { return __uint_as_float(u & 0xffff0000u); }

// ---------------- CSR build: bucket sort ----------------

__global__ __launch_bounds__(256) void k_phaseA(const int* __restrict__ dst,
                                                int* __restrict__ Cm) {
    __shared__ int hist[NB];
    int blk = blockIdx.x, t = threadIdx.x;
    if (t < NB) hist[t] = 0;
    __syncthreads();
    int base = blk * EPB;
#pragma unroll 5
    for (int k = 0; k < EPB / 256; k++) {
        int d = dst[base + k * 256 + t];
        atomicAdd(&hist[d >> 9], 1);
    }
    __syncthreads();
    if (t < NB) Cm[blk * NB + t] = hist[t];
}

// parallel scan of Cm over blocks: one block per bucket
__global__ __launch_bounds__(256) void k_scanBkt(int* __restrict__ Cm,
                                                 int* __restrict__ bktSum) {
    __shared__ int sdata[256];
    int b = blockIdx.x, t = threadIdx.x;
    int v = (t < NBLK) ? Cm[t * NB + b] : 0;
    sdata[t] = v;
    __syncthreads();
    int val = v;
    for (int off = 1; off < 256; off <<= 1) {
        int tmp = (t >= off) ? sdata[t - off] : 0;
        __syncthreads();
        val += tmp;
        sdata[t] = val;
        __syncthreads();
    }
    if (t < NBLK) Cm[t * NB + b] = val - v;   // exclusive prefix within bucket
    if (t == 255) bktSum[b] = val;
}

__global__ __launch_bounds__(256) void k_scanBase(const int* __restrict__ bktSum,
                                                  int* __restrict__ bktBase) {
    __shared__ int sdata[256];
    int t = threadIdx.x;
    int v = (t < NB) ? bktSum[t] : 0;
    sdata[t] = v;
    __syncthreads();
    int val = v;
    for (int off = 1; off < 256; off <<= 1) {
        int tmp = (t >= off) ? sdata[t - off] : 0;
        __syncthreads();
        val += tmp;
        sdata[t] = val;
        __syncthreads();
    }
    if (t < NB) bktBase[t] = val - v;
    if (t == 0) bktBase[NB] = N_EDGES;
}

__global__ __launch_bounds__(256) void k_phaseB(const int* __restrict__ src,
                                                const int* __restrict__ dst,
                                                const int* __restrict__ Cm,
                                                const int* __restrict__ bktBase,
                                                unsigned int* __restrict__ bucketed) {
    __shared__ int offs[NB];
    int blk = blockIdx.x, t = threadIdx.x;
    if (t < NB) offs[t] = Cm[blk * NB + t] + bktBase[t];
    __syncthreads();
    int base = blk * EPB;
#pragma unroll 5
    for (int k = 0; k < EPB / 256; k++) {
        int e = base + k * 256 + t;
        int d = dst[e];
        int sv = src[e];
        int pos = atomicAdd(&offs[d >> 9], 1);
        bucketed[pos] = ((unsigned int)sv << 9) | (unsigned int)(d & 511);
    }
}

__global__ __launch_bounds__(512) void k_phaseC(const unsigned int* __restrict__ bucketed,
                                                const int* __restrict__ bktBase,
                                                int* __restrict__ rowptr,
                                                float* __restrict__ dinvg,
                                                int* __restrict__ csr_src) {
    __shared__ int cnt[512];
    __shared__ int cur[512];
    __shared__ int sdata[512];
    int b = blockIdx.x, t = threadIdx.x;
    int base = bktBase[b], endR = bktBase[b + 1];
    int nodeBase = b << 9;
    int nNodes = N_NODES - nodeBase;
    if (nNodes > 512) nNodes = 512;

    cnt[t] = 0;
    __syncthreads();
    for (int e = base + t; e < endR; e += 512)
        atomicAdd(&cnt[bucketed[e] & 511], 1);
    __syncthreads();

    int s = cnt[t];
    sdata[t] = s;
    __syncthreads();
    int val = s;
    for (int off = 1; off < 512; off <<= 1) {
        int tmp = (t >= off) ? sdata[t - off] : 0;
        __syncthreads();
        val += tmp;
        sdata[t] = val;
        __syncthreads();
    }
    cur[t] = val - s;
    if (t < nNodes) {
        rowptr[nodeBase + t] = base + val - s;
        dinvg[nodeBase + t] = rsqrtf((float)s + 1.0f);
    }
    if (b == NB - 1 && t == 0) rowptr[N_NODES] = N_EDGES;
    __syncthreads();

    for (int e = base + t; e < endR; e += 512) {
        unsigned int u = bucketed[e];
        int pos = base + atomicAdd(&cur[u & 511], 1);
        csr_src[pos] = (int)(u >> 9);
    }
}

// ---------------- W prep: transpose to bf16 [n][k], fuse mu|ls concat -------

__global__ __launch_bounds__(256) void k_prepW(const float* __restrict__ W1,
                                               const float* __restrict__ Wmu,
                                               const float* __restrict__ Wls,
                                               unsigned short* __restrict__ Wt1,
                                               unsigned short* __restrict__ WtC) {
    int idx = blockIdx.x * 256 + threadIdx.x;
    int n = idx >> 7, k = idx & 127;
    Wt1[idx] = f2bf(W1[k * 128 + n]);
    WtC[idx] = f2bf((n < 64) ? Wmu[k * 64 + n] : Wls[k * 64 + (n - 64)]);
}

// ---------------- MFMA GEMM1: x[f32] @ W1 -> h0p (sliced bf16) -------------
// Output layout: h0p[slice][node][16ch], slice = col>>4 (8 slices of 16 ch).

#define LDA 136

__global__ __launch_bounds__(256) void k_gemm1(const float* __restrict__ X,
                                               const unsigned short* __restrict__ Wt,
                                               unsigned short* __restrict__ Y) {
    __shared__ unsigned short sA[128 * LDA];
    int t = threadIdx.x;
    int R0 = blockIdx.x * 128;
    int row = t >> 1, colb = (t & 1) * 64;
    bool valid = (R0 + row) < N_NODES;
    const float* Xr = X + (size_t)(R0 + row) * 128 + colb;
    unsigned short* dp = sA + row * LDA + colb;
#pragma unroll
    for (int j = 0; j < 16; j++) {
        float4 v = valid ? *(const float4*)(Xr + j * 4) : make_float4(0.f, 0.f, 0.f, 0.f);
        ushort4 o;
        o.x = f2bf(v.x); o.y = f2bf(v.y); o.z = f2bf(v.z); o.w = f2bf(v.w);
        *(ushort4*)(dp + j * 4) = o;
    }
    __syncthreads();

    int wv = t >> 6, l = t & 63;
    int quad = l >> 4, lm = l & 15;

    bf16x8 a[2][4];
#pragma unroll
    for (int mt = 0; mt < 2; mt++)
#pragma unroll
        for (int ks = 0; ks < 4; ks++)
            a[mt][ks] = *(const bf16x8*)(sA + (wv * 32 + mt * 16 + lm) * LDA +
                                         ks * 32 + quad * 8);

    f32x4 acc[2][8] = {};
#pragma unroll
    for (int nt = 0; nt < 8; nt++) {
        bf16x8 b[4];
        const unsigned short* Wp = Wt + (nt * 16 + lm) * 128 + quad * 8;
#pragma unroll
        for (int ks = 0; ks < 4; ks++)
            b[ks] = *(const bf16x8*)(Wp + ks * 32);
#pragma unroll
        for (int mt = 0; mt < 2; mt++) {
            f32x4 c = acc[mt][nt];
#pragma unroll
            for (int ks = 0; ks < 4; ks++)
                c = __builtin_amdgcn_mfma_f32_16x16x32_bf16(a[mt][ks], b[ks], c, 0, 0, 0);
            acc[mt][nt] = c;
        }
    }

    int rbase = R0 + wv * 32 + quad * 4;
#pragma unroll
    for (int mt = 0; mt < 2; mt++)
#pragma unroll
        for (int nt = 0; nt < 8; nt++)
#pragma unroll
            for (int reg = 0; reg < 4; reg++) {
                int r = rbase + mt * 16 + reg;
                if (r < N_NODES)
                    Y[((size_t)nt * N_NODES + r) * 16 + lm] = f2bf(acc[mt][nt][reg]);
            }
}

// ------------- XCD-sliced aggregation ---------------------------------------
// slice = blockIdx & 7 -> pins each 16-channel slice (3.2 MB) to one XCD's L2.
// Wave: 16 quads, one node each; quad lane ql owns 4 channels (uint2 gather).
// LAYER 1: in = h0p (sliced), out = hbp (sliced), +b1, relu.
// LAYER 2: in = hbp (sliced), out = g (node-major bf16) for k_gemm2.

template<int LAYER>
__global__ __launch_bounds__(256) void k_aggs(const unsigned short* __restrict__ Hin,
                                              const int* __restrict__ rowptr,
                                              const int* __restrict__ csr_src,
                                              const float* __restrict__ dinv,
                                              const float* __restrict__ bias,
                                              unsigned short* __restrict__ Hout) {
    int t = threadIdx.x;
    int wv = t >> 6, l = t & 63;
    int slice = blockIdx.x & 7;
    int blkn = blockIdx.x >> 3;
    int quad = l >> 2, ql = l & 3;
    int i = blkn * 64 + wv * 16 + quad;
    bool vnode = i < N_NODES;
    int il = vnode ? i : 0;
    const unsigned short* Hs = Hin + (size_t)slice * (N_NODES * 16);

    float di = dinv[il];
    int beg = vnode ? rowptr[il] : 0;
    int end = vnode ? rowptr[il + 1] : 0;
    int deg = end - beg;

    // wave-wide max degree (deg is quad-uniform)
    int md = deg;
    md = max(md, __shfl_xor(md, 4));
    md = max(md, __shfl_xor(md, 8));
    md = max(md, __shfl_xor(md, 16));
    md = max(md, __shfl_xor(md, 32));
    md = __builtin_amdgcn_readfirstlane(md);

    // self-loop contribution: norm = di*di
    uint2 sv = *(const uint2*)(Hs + (size_t)il * 16 + ql * 4);
    float nn = di * di;
    float a0 = bfl(sv.x) * nn, a1 = bfh(sv.x) * nn;
    float a2 = bfl(sv.y) * nn, a3 = bfh(sv.y) * nn;

    for (int p = 0; p < md; p += 8) {
        int s[8]; float n[8]; uint2 r[8];
#pragma unroll
        for (int j = 0; j < 8; j++) {
            int q = beg + p + j;
            int qc = q < end ? q : end - 1;
            qc = qc < 0 ? 0 : qc;
            s[j] = __builtin_nontemporal_load(csr_src + qc);
        }
#pragma unroll
        for (int j = 0; j < 8; j++) n[j] = dinv[s[j]];
#pragma unroll
        for (int j = 0; j < 8; j++)
            r[j] = *(const uint2*)(Hs + (size_t)s[j] * 16 + ql * 4);
#pragma unroll
        for (int j = 0; j < 8; j++) n[j] = (beg + p + j < end) ? n[j] * di : 0.f;
#pragma unroll
        for (int j = 0; j < 8; j++) {
            a0 = fmaf(bfl(r[j].x), n[j], a0);
            a1 = fmaf(bfh(r[j].x), n[j], a1);
            a2 = fmaf(bfl(r[j].y), n[j], a2);
            a3 = fmaf(bfh(r[j].y), n[j], a3);
        }
    }

    if (!vnode) return;

    if (LAYER == 1) {
        const float4 bv = *(const float4*)(bias + slice * 16 + ql * 4);
        a0 += bv.x; a1 += bv.y; a2 += bv.z; a3 += bv.w;
        a0 = a0 > 0.f ? a0 : 0.f;
        a1 = a1 > 0.f ? a1 : 0.f;
        a2 = a2 > 0.f ? a2 : 0.f;
        a3 = a3 > 0.f ? a3 : 0.f;
        uint2 o;
        o.x = ((unsigned int)f2bf(a1) << 16) | (unsigned int)f2bf(a0);
        o.y = ((unsigned int)f2bf(a3) << 16) | (unsigned int)f2bf(a2);
        *(uint2*)(Hout + ((size_t)slice * N_NODES + i) * 16 + ql * 4) = o;
    } else {
        uint2 o;
        o.x = ((unsigned int)f2bf(a1) << 16) | (unsigned int)f2bf(a0);
        o.y = ((unsigned int)f2bf(a3) << 16) | (unsigned int)f2bf(a2);
        *(uint2*)(Hout + (size_t)i * 128 + slice * 16 + ql * 4) = o;
    }
}

// ---------------- MFMA GEMM2: g[bf16] @ WtC + bias -> out ------------------

__global__ __launch_bounds__(256) void k_gemm2(const unsigned short* __restrict__ G,
                                               const unsigned short* __restrict__ Wt,
                                               const float* __restrict__ bmu,
                                               const float* __restrict__ bls,
                                               float* __restrict__ out) {
    __shared__ unsigned short sA[128 * LDA];
    int t = threadIdx.x;
    int R0 = blockIdx.x * 128;
    int row = t >> 1, colb = (t & 1) * 64;
    bool valid = (R0 + row) < N_NODES;
    const unsigned short* Gr = G + (size_t)(R0 + row) * 128 + colb;
    unsigned short* dp = sA + row * LDA + colb;
#pragma unroll
    for (int j = 0; j < 8; j++) {
        bf16x8 v = {0, 0, 0, 0, 0, 0, 0, 0};
        if (valid) v = *(const bf16x8*)(Gr + j * 8);
        *(bf16x8*)(dp + j * 8) = v;
    }
    __syncthreads();

    int wv = t >> 6, l = t & 63;
    int quad = l >> 4, lm = l & 15;

    bf16x8 a[2][4];
#pragma unroll
    for (int mt = 0; mt < 2; mt++)
#pragma unroll
        for (int ks = 0; ks < 4; ks++)
            a[mt][ks] = *(const bf16x8*)(sA + (wv * 32 + mt * 16 + lm) * LDA +
                                         ks * 32 + quad * 8);

    f32x4 acc[2][8] = {};
#pragma unroll
    for (int nt = 0; nt < 8; nt++) {
        bf16x8 b[4];
        const unsigned short* Wp = Wt + (nt * 16 + lm) * 128 + quad * 8;
#pragma unroll
        for (int ks = 0; ks < 4; ks++)
            b[ks] = *(const bf16x8*)(Wp + ks * 32);
#pragma unroll
        for (int mt = 0; mt < 2; mt++) {
            f32x4 c = acc[mt][nt];
#pragma unroll
            for (int ks = 0; ks < 4; ks++)
                c = __builtin_amdgcn_mfma_f32_16x16x32_bf16(a[mt][ks], b[ks], c, 0, 0, 0);
            acc[mt][nt] = c;
        }
    }

    int rbase = R0 + wv * 32 + quad * 4;
#pragma unroll
    for (int mt = 0; mt < 2; mt++)
#pragma unroll
        for (int nt = 0; nt < 8; nt++) {
            int col = nt * 16 + lm;
#pragma unroll
            for (int reg = 0; reg < 4; reg++) {
                int r = rbase + mt * 16 + reg;
                if (r < N_NODES) {
                    float v = acc[mt][nt][reg];
                    if (col < 64)
                        out[(size_t)r * 64 + col] = v + bmu[col];
                    else
                        out[(size_t)N_NODES * 64 + (size_t)r * 64 + (col - 64)] = v + bls[col - 64];
                }
            }
        }
}

// ---------------- launch ----------------

extern "C" void kernel_launch(void* const* d_in, const int* in_sizes, int n_in,
                              void* d_out, int out_size, void* d_ws, size_t ws_size,
                              hipStream_t stream) {
    const float* x    = (const float*)d_in[0];
    const int*   ei   = (const int*)d_in[1];
    const float* W1   = (const float*)d_in[2];
    const float* b1   = (const float*)d_in[3];
    const float* Wmu  = (const float*)d_in[4];
    const float* bmu  = (const float*)d_in[5];
    const float* Wls  = (const float*)d_in[6];
    const float* bls  = (const float*)d_in[7];
    const int* src = ei;
    const int* dst = ei + N_EDGES;

    char* p = (char*)d_ws;
    unsigned short* bufA = (unsigned short*)p; p += (size_t)N_NODES * 128 * 2; // h0p sliced, later g node-major
    unsigned short* bufH = (unsigned short*)p; p += (size_t)N_NODES * 128 * 2; // hbp sliced
    unsigned short* Wt1  = (unsigned short*)p; p += 128 * 128 * 2;
    unsigned short* WtC  = (unsigned short*)p; p += 128 * 128 * 2;
    int*   Cm      = (int*)p;   p += (size_t)NBLK * NB * 4;
    int*   bktSum  = (int*)p;   p += 256 * 4;
    int*   bktBase = (int*)p;   p += 256 * 4;
    int*   rowptr  = (int*)p;   p += 400016;
    float* dinv    = (float*)p; p += 400000;
    unsigned int* bucketed = (unsigned int*)p; p += (size_t)N_EDGES * 4;
    int*   csr_src = (int*)p;   p += (size_t)N_EDGES * 4;

    // CSR build
    k_phaseA<<<NBLK, 256, 0, stream>>>(dst, Cm);
    k_scanBkt<<<NB, 256, 0, stream>>>(Cm, bktSum);
    k_scanBase<<<1, 256, 0, stream>>>(bktSum, bktBase);
    k_phaseB<<<NBLK, 256, 0, stream>>>(src, dst, Cm, bktBase, bucketed);
    k_phaseC<<<NB, 512, 0, stream>>>(bucketed, bktBase, rowptr, dinv, csr_src);

    k_prepW<<<64, 256, 0, stream>>>(W1, Wmu, Wls, Wt1, WtC);

    int gblk = (N_NODES + 127) / 128;   // 782
    int aggblk = ((N_NODES + 63) / 64) * 8;   // 1563 * 8 = 12504

    // layer 1: h0p = x @ W1 (sliced layout) ; hbp = relu(agg(h0p) + b1)
    k_gemm1<<<gblk, 256, 0, stream>>>(x, Wt1, bufA);
    k_aggs<1><<<aggblk, 256, 0, stream>>>(bufA, rowptr, csr_src, dinv, b1, bufH);

    // layer 2: g = agg(hbp) (node-major, aliases bufA) ; out = g @ [Wmu|Wls] + bias
    k_aggs<2><<<aggblk, 256, 0, stream>>>(bufH, rowptr, csr_src, dinv, bmu, bufA);
    k_gemm2<<<gblk, 256, 0, stream>>>(bufA, WtC, bmu, bls, (float*)d_out);
}

// Round 3
// 348.179 us; speedup vs baseline: 2.1715x; 2.1715x over previous
//
#include <hip/hip_runtime.h>
#include <hip/hip_bf16.h>
#include <stdint.h>

#define N_NODES 100000
#define IN_CH   128
#define HID     128
#define OUT_CH  64
#define N_EDGES 1600000

#define NB    196      // buckets of 512 nodes
#define NBLK  250      // edge-partition blocks for phases A/B
#define EPB   6400     // edges per block

typedef __attribute__((ext_vector_type(8))) short  bf16x8;
typedef __attribute__((ext_vector_type(4))) float  f32x4;

// ---------------- helpers ----------------

__device__ __forceinline__ unsigned short f2bf(float f) {   // RNE f32->bf16
    unsigned int u = __float_as_uint(f);
    u = (u + 0x7fffu + ((u >> 16) & 1u)) >> 16;
    return (unsigned short)u;
}
__device__ __forceinline__ float bfl(unsigned int u) { return __uint_as_float(u << 16); }
__device__ __forceinline__ float bfh(unsigned int u) { return __uint_as_float(u & 0xffff0000u); }

// ---------------- CSR build: bucket sort ----------------

__global__ __launch_bounds__(256) void k_phaseA(const int* __restrict__ dst,
                                                int* __restrict__ Cm) {
    __shared__ int hist[NB];
    int blk = blockIdx.x, t = threadIdx.x;
    if (t < NB) hist[t] = 0;
    __syncthreads();
    int base = blk * EPB;
#pragma unroll 5
    for (int k = 0; k < EPB / 256; k++) {
        int d = dst[base + k * 256 + t];
        atomicAdd(&hist[d >> 9], 1);
    }
    __syncthreads();
    if (t < NB) Cm[blk * NB + t] = hist[t];
}

// parallel scan of Cm over blocks: one block per bucket
__global__ __launch_bounds__(256) void k_scanBkt(int* __restrict__ Cm,
                                                 int* __restrict__ bktSum) {
    __shared__ int sdata[256];
    int b = blockIdx.x, t = threadIdx.x;
    int v = (t < NBLK) ? Cm[t * NB + b] : 0;
    sdata[t] = v;
    __syncthreads();
    int val = v;
    for (int off = 1; off < 256; off <<= 1) {
        int tmp = (t >= off) ? sdata[t - off] : 0;
        __syncthreads();
        val += tmp;
        sdata[t] = val;
        __syncthreads();
    }
    if (t < NBLK) Cm[t * NB + b] = val - v;   // exclusive prefix within bucket
    if (t == 255) bktSum[b] = val;
}

__global__ __launch_bounds__(256) void k_scanBase(const int* __restrict__ bktSum,
                                                  int* __restrict__ bktBase) {
    __shared__ int sdata[256];
    int t = threadIdx.x;
    int v = (t < NB) ? bktSum[t] : 0;
    sdata[t] = v;
    __syncthreads();
    int val = v;
    for (int off = 1; off < 256; off <<= 1) {
        int tmp = (t >= off) ? sdata[t - off] : 0;
        __syncthreads();
        val += tmp;
        sdata[t] = val;
        __syncthreads();
    }
    if (t < NB) bktBase[t] = val - v;
    if (t == 0) bktBase[NB] = N_EDGES;
}

__global__ __launch_bounds__(256) void k_phaseB(const int* __restrict__ src,
                                                const int* __restrict__ dst,
                                                const int* __restrict__ Cm,
                                                const int* __restrict__ bktBase,
                                                unsigned int* __restrict__ bucketed) {
    __shared__ int offs[NB];
    int blk = blockIdx.x, t = threadIdx.x;
    if (t < NB) offs[t] = Cm[blk * NB + t] + bktBase[t];
    __syncthreads();
    int base = blk * EPB;
#pragma unroll 5
    for (int k = 0; k < EPB / 256; k++) {
        int e = base + k * 256 + t;
        int d = dst[e];
        int sv = src[e];
        int pos = atomicAdd(&offs[d >> 9], 1);
        bucketed[pos] = ((unsigned int)sv << 9) | (unsigned int)(d & 511);
    }
}

__global__ __launch_bounds__(512) void k_phaseC(const unsigned int* __restrict__ bucketed,
                                                const int* __restrict__ bktBase,
                                                int* __restrict__ rowptr,
                                                float* __restrict__ dinvg,
                                                int* __restrict__ csr_src) {
    __shared__ int cnt[512];
    __shared__ int cur[512];
    __shared__ int sdata[512];
    int b = blockIdx.x, t = threadIdx.x;
    int base = bktBase[b], endR = bktBase[b + 1];
    int nodeBase = b << 9;
    int nNodes = N_NODES - nodeBase;
    if (nNodes > 512) nNodes = 512;

    cnt[t] = 0;
    __syncthreads();
    for (int e = base + t; e < endR; e += 512)
        atomicAdd(&cnt[bucketed[e] & 511], 1);
    __syncthreads();

    int s = cnt[t];
    sdata[t] = s;
    __syncthreads();
    int val = s;
    for (int off = 1; off < 512; off <<= 1) {
        int tmp = (t >= off) ? sdata[t - off] : 0;
        __syncthreads();
        val += tmp;
        sdata[t] = val;
        __syncthreads();
    }
    cur[t] = val - s;
    if (t < nNodes) {
        rowptr[nodeBase + t] = base + val - s;
        dinvg[nodeBase + t] = rsqrtf((float)s + 1.0f);
    }
    if (b == NB - 1 && t == 0) rowptr[N_NODES] = N_EDGES;
    __syncthreads();

    for (int e = base + t; e < endR; e += 512) {
        unsigned int u = bucketed[e];
        int pos = base + atomicAdd(&cur[u & 511], 1);
        csr_src[pos] = (int)(u >> 9);
    }
}

// ---------------- W prep: transpose to bf16 [n][k], fuse mu|ls concat -------

__global__ __launch_bounds__(256) void k_prepW(const float* __restrict__ W1,
                                               const float* __restrict__ Wmu,
                                               const float* __restrict__ Wls,
                                               unsigned short* __restrict__ Wt1,
                                               unsigned short* __restrict__ WtC) {
    int idx = blockIdx.x * 256 + threadIdx.x;
    int n = idx >> 7, k = idx & 127;
    Wt1[idx] = f2bf(W1[k * 128 + n]);
    WtC[idx] = f2bf((n < 64) ? Wmu[k * 64 + n] : Wls[k * 64 + (n - 64)]);
}

// ------ MFMA GEMM1: h0' = dinv * (x @ W1), node-major bf16 [node][128] ------

#define LDA 136

__global__ __launch_bounds__(256) void k_gemm1(const float* __restrict__ X,
                                               const unsigned short* __restrict__ Wt,
                                               const float* __restrict__ dinv,
                                               unsigned short* __restrict__ Y) {
    __shared__ unsigned short sA[128 * LDA];
    int t = threadIdx.x;
    int R0 = blockIdx.x * 128;
    int row = t >> 1, colb = (t & 1) * 64;
    bool valid = (R0 + row) < N_NODES;
    const float* Xr = X + (size_t)(R0 + row) * 128 + colb;
    unsigned short* dp = sA + row * LDA + colb;
#pragma unroll
    for (int j = 0; j < 16; j++) {
        float4 v = valid ? *(const float4*)(Xr + j * 4) : make_float4(0.f, 0.f, 0.f, 0.f);
        ushort4 o;
        o.x = f2bf(v.x); o.y = f2bf(v.y); o.z = f2bf(v.z); o.w = f2bf(v.w);
        *(ushort4*)(dp + j * 4) = o;
    }
    __syncthreads();

    int wv = t >> 6, l = t & 63;
    int quad = l >> 4, lm = l & 15;

    bf16x8 a[2][4];
#pragma unroll
    for (int mt = 0; mt < 2; mt++)
#pragma unroll
        for (int ks = 0; ks < 4; ks++)
            a[mt][ks] = *(const bf16x8*)(sA + (wv * 32 + mt * 16 + lm) * LDA +
                                         ks * 32 + quad * 8);

    f32x4 acc[2][8] = {};
#pragma unroll
    for (int nt = 0; nt < 8; nt++) {
        bf16x8 b[4];
        const unsigned short* Wp = Wt + (nt * 16 + lm) * 128 + quad * 8;
#pragma unroll
        for (int ks = 0; ks < 4; ks++)
            b[ks] = *(const bf16x8*)(Wp + ks * 32);
#pragma unroll
        for (int mt = 0; mt < 2; mt++) {
            f32x4 c = acc[mt][nt];
#pragma unroll
            for (int ks = 0; ks < 4; ks++)
                c = __builtin_amdgcn_mfma_f32_16x16x32_bf16(a[mt][ks], b[ks], c, 0, 0, 0);
            acc[mt][nt] = c;
        }
    }

    int rbase = R0 + wv * 32 + quad * 4;
    float dv[2][4];
#pragma unroll
    for (int mt = 0; mt < 2; mt++)
#pragma unroll
        for (int reg = 0; reg < 4; reg++) {
            int r = rbase + mt * 16 + reg;
            dv[mt][reg] = (r < N_NODES) ? dinv[r] : 0.f;
        }
#pragma unroll
    for (int mt = 0; mt < 2; mt++)
#pragma unroll
        for (int nt = 0; nt < 8; nt++)
#pragma unroll
            for (int reg = 0; reg < 4; reg++) {
                int r = rbase + mt * 16 + reg;
                if (r < N_NODES)
                    Y[(size_t)r * 128 + nt * 16 + lm] = f2bf(acc[mt][nt][reg] * dv[mt][reg]);
            }
}

// -------- agg1: hb' = dinv * relu(dinv * (self + sum h0') + b1) -------------
// Inputs pre-scaled (h0' = d*h0): per-edge weight is 1, no dinv gather.
// Batch-32 window: 32 gathers in flight, one csr->rows chain per node (typ).

__global__ __launch_bounds__(256) void k_agg1(const unsigned short* __restrict__ h0,
                                              const int* __restrict__ rowptr,
                                              const int* __restrict__ csr_src,
                                              const float* __restrict__ dinv,
                                              const float* __restrict__ b1,
                                              unsigned short* __restrict__ hb) {
    int lane = threadIdx.x & 63;
    int i = __builtin_amdgcn_readfirstlane(blockIdx.x * 4 + (threadIdx.x >> 6));
    int c2 = lane * 2;
    float di = dinv[i];
    unsigned int sv = *(const unsigned int*)(h0 + (size_t)i * 128 + c2);
    float ax = bfl(sv), ay = bfh(sv);            // self term, weight 1
    int beg = rowptr[i], end = rowptr[i + 1];
    for (int p = beg; p < end; p += 32) {
        int s[32]; unsigned int r[32];
#pragma unroll
        for (int j = 0; j < 32; j++) {
            int q = p + j;
            s[j] = csr_src[q < end ? q : end - 1];
        }
#pragma unroll
        for (int j = 0; j < 32; j++)
            r[j] = *(const unsigned int*)(h0 + (size_t)s[j] * 128 + c2);
#pragma unroll
        for (int j = 0; j < 32; j++) {
            unsigned int v = (p + j < end) ? r[j] : 0u;
            ax += bfl(v);
            ay += bfh(v);
        }
    }
    ax = ax * di + b1[c2];
    ay = ay * di + b1[c2 + 1];
    ax = ax > 0.f ? ax : 0.f;
    ay = ay > 0.f ? ay : 0.f;
    ax *= di;                                    // pre-scale for layer-2 gather
    ay *= di;
    unsigned int pk = ((unsigned int)f2bf(ay) << 16) | (unsigned int)f2bf(ax);
    *(unsigned int*)(hb + (size_t)i * 128 + c2) = pk;
}

// ------- fused layer 2: g = dinv*(self + sum hb'); out = g @ WtC + bias -----
// Block = 256 thr / 4 waves / 16 nodes. Same batch-32 pre-scaled gather loop.

#define LDG 136

__global__ __launch_bounds__(256) void k_agg2g(const unsigned short* __restrict__ hb,
                                               const int* __restrict__ rowptr,
                                               const int* __restrict__ csr_src,
                                               const float* __restrict__ dinv,
                                               const unsigned short* __restrict__ WtC,
                                               const float* __restrict__ bmu,
                                               const float* __restrict__ bls,
                                               float* __restrict__ out) {
    __shared__ unsigned short g[16 * LDG];
    int t = threadIdx.x;
    int wv = t >> 6, lane = t & 63;
    int nodeBase = blockIdx.x * 16;
    int c2 = lane * 2;

#pragma unroll 1
    for (int j4 = 0; j4 < 4; j4++) {
        int i = __builtin_amdgcn_readfirstlane(nodeBase + wv * 4 + j4);
        float di = dinv[i];
        unsigned int sv = *(const unsigned int*)(hb + (size_t)i * 128 + c2);
        float ax = bfl(sv), ay = bfh(sv);
        int beg = rowptr[i], end = rowptr[i + 1];
        for (int p = beg; p < end; p += 32) {
            int s[32]; unsigned int r[32];
#pragma unroll
            for (int j = 0; j < 32; j++) {
                int q = p + j;
                s[j] = csr_src[q < end ? q : end - 1];
            }
#pragma unroll
            for (int j = 0; j < 32; j++)
                r[j] = *(const unsigned int*)(hb + (size_t)s[j] * 128 + c2);
#pragma unroll
            for (int j = 0; j < 32; j++) {
                unsigned int v = (p + j < end) ? r[j] : 0u;
                ax += bfl(v);
                ay += bfh(v);
            }
        }
        ax *= di;
        ay *= di;
        unsigned int pk = ((unsigned int)f2bf(ay) << 16) | (unsigned int)f2bf(ax);
        *(unsigned int*)(g + (wv * 4 + j4) * LDG + c2) = pk;
    }
    __syncthreads();

    // MFMA: wave wv computes output cols [wv*32, wv*32+32)
    int quad = lane >> 4, lm = lane & 15;
    bf16x8 a[4];
#pragma unroll
    for (int ks = 0; ks < 4; ks++)
        a[ks] = *(const bf16x8*)(g + lm * LDG + ks * 32 + quad * 8);

#pragma unroll
    for (int nt2 = 0; nt2 < 2; nt2++) {
        int nt = wv * 2 + nt2;
        f32x4 acc = {};
        const unsigned short* Wp = WtC + (nt * 16 + lm) * 128 + quad * 8;
#pragma unroll
        for (int ks = 0; ks < 4; ks++) {
            bf16x8 b = *(const bf16x8*)(Wp + ks * 32);
            acc = __builtin_amdgcn_mfma_f32_16x16x32_bf16(a[ks], b, acc, 0, 0, 0);
        }
        int col = nt * 16 + lm;
#pragma unroll
        for (int reg = 0; reg < 4; reg++) {
            int row = nodeBase + quad * 4 + reg;
            float v = acc[reg];
            if (col < 64)
                out[(size_t)row * 64 + col] = v + bmu[col];
            else
                out[(size_t)N_NODES * 64 + (size_t)row * 64 + (col - 64)] = v + bls[col - 64];
        }
    }
}

// ---------------- launch ----------------

extern "C" void kernel_launch(void* const* d_in, const int* in_sizes, int n_in,
                              void* d_out, int out_size, void* d_ws, size_t ws_size,
                              hipStream_t stream) {
    const float* x    = (const float*)d_in[0];
    const int*   ei   = (const int*)d_in[1];
    const float* W1   = (const float*)d_in[2];
    const float* b1   = (const float*)d_in[3];
    const float* Wmu  = (const float*)d_in[4];
    const float* bmu  = (const float*)d_in[5];
    const float* Wls  = (const float*)d_in[6];
    const float* bls  = (const float*)d_in[7];
    const int* src = ei;
    const int* dst = ei + N_EDGES;

    char* p = (char*)d_ws;
    unsigned short* bufA = (unsigned short*)p; p += (size_t)N_NODES * 128 * 2; // h0' (bf16, pre-scaled)
    unsigned short* bufH = (unsigned short*)p; p += (size_t)N_NODES * 128 * 2; // hb' (bf16, pre-scaled)
    unsigned short* Wt1  = (unsigned short*)p; p += 128 * 128 * 2;
    unsigned short* WtC  = (unsigned short*)p; p += 128 * 128 * 2;
    int*   Cm      = (int*)p;   p += (size_t)NBLK * NB * 4;
    int*   bktSum  = (int*)p;   p += 256 * 4;
    int*   bktBase = (int*)p;   p += 256 * 4;
    int*   rowptr  = (int*)p;   p += 400016;
    float* dinv    = (float*)p; p += 400000;
    unsigned int* bucketed = (unsigned int*)p; p += (size_t)N_EDGES * 4;
    int*   csr_src = (int*)p;   p += (size_t)N_EDGES * 4;

    // CSR build
    k_phaseA<<<NBLK, 256, 0, stream>>>(dst, Cm);
    k_scanBkt<<<NB, 256, 0, stream>>>(Cm, bktSum);
    k_scanBase<<<1, 256, 0, stream>>>(bktSum, bktBase);
    k_phaseB<<<NBLK, 256, 0, stream>>>(src, dst, Cm, bktBase, bucketed);
    k_phaseC<<<NB, 512, 0, stream>>>(bucketed, bktBase, rowptr, dinv, csr_src);

    k_prepW<<<64, 256, 0, stream>>>(W1, Wmu, Wls, Wt1, WtC);

    int gblk = (N_NODES + 127) / 128;   // 782

    // layer 1: h0' = dinv * (x @ W1) (MFMA) ; hb' = dinv*relu(dinv*agg + b1)
    k_gemm1<<<gblk, 256, 0, stream>>>(x, Wt1, dinv, bufA);
    k_agg1<<<N_NODES / 4, 256, 0, stream>>>(bufA, rowptr, csr_src, dinv, b1, bufH);

    // layer 2 (reordered): out = (dinv*(self+sum hb')) @ [Wmu|Wls] + bias, fused
    k_agg2g<<<N_NODES / 16, 256, 0, stream>>>(bufH, rowptr, csr_src, dinv,
                                              WtC, bmu, bls, (float*)d_out);
}